// Round 4
// baseline (867.244 us; speedup 1.0000x reference)
//
#include <hip/hip_runtime.h>

typedef unsigned short u16;
typedef __attribute__((ext_vector_type(8))) short bf16x8;   // 8 bf16 (4 VGPRs)
typedef __attribute__((ext_vector_type(4))) float f32x4;

#define D_EMB 1024
#define NBAT  256
#define AS1 __attribute__((address_space(1)))
#define AS3 __attribute__((address_space(3)))

__device__ __forceinline__ u16 f2bf(float f){
    unsigned int u = __float_as_uint(f);
    unsigned int r = (u + 0x7fffu + ((u >> 16) & 1u)) >> 16;  // RNE
    return (u16)r;
}
__device__ __forceinline__ float leaky(float x){ return x > 0.f ? x : 0.1f * x; }

// ---------------------------------------------------------------------------
// Pack img_emb(+pool_img as row 36) and cap_emb(+pool_txt as row 40) to bf16.
// imgw: [256][37][1024] bf16, capw: [256][41][1024] bf16
// ---------------------------------------------------------------------------
__global__ void pack_kernel(const float* __restrict__ pool_img, const float* __restrict__ img_emb,
                            const float* __restrict__ pool_txt, const float* __restrict__ cap_emb,
                            u16* __restrict__ imgw, u16* __restrict__ capw){
    int row = blockIdx.x;            // 0..19967
    const float* src; u16* dst;
    if (row < NBAT * 37){
        int e = row / 37, rr = row - e * 37;
        src = (rr < 36) ? (img_emb + ((size_t)e * 36 + rr) * D_EMB) : (pool_img + (size_t)e * D_EMB);
        dst = imgw + (size_t)row * D_EMB;
    } else {
        int r2 = row - NBAT * 37;
        int e = r2 / 41, rr = r2 - e * 41;
        src = (rr < 40) ? (cap_emb + ((size_t)e * 40 + rr) * D_EMB) : (pool_txt + (size_t)e * D_EMB);
        dst = capw + (size_t)r2 * D_EMB;
    }
    int t = threadIdx.x;             // 256 threads, 4 floats each
    float4 v = ((const float4*)src)[t];
    unsigned long long pk = (unsigned long long)f2bf(v.x)
        | ((unsigned long long)f2bf(v.y) << 16)
        | ((unsigned long long)f2bf(v.z) << 32)
        | ((unsigned long long)f2bf(v.w) << 48);
    *(unsigned long long*)(dst + (size_t)t * 4) = pk;
}

// ---------------------------------------------------------------------------
// Pool-vector norms
// ---------------------------------------------------------------------------
__global__ void norm_kernel(const float* __restrict__ pool_img, const float* __restrict__ pool_txt,
                            float* __restrict__ w1i, float* __restrict__ w1t){
    __shared__ float red[256];
    int v = blockIdx.x;              // 0..511
    const float* src = (v < 256) ? (pool_img + (size_t)v * D_EMB)
                                 : (pool_txt + (size_t)(v - 256) * D_EMB);
    int t = threadIdx.x;
    float4 x = ((const float4*)src)[t];
    red[t] = x.x*x.x + x.y*x.y + x.z*x.z + x.w*x.w;
    __syncthreads();
    for (int off = 128; off > 0; off >>= 1){
        if (t < off) red[t] += red[t + off];
        __syncthreads();
    }
    if (t == 0){
        float n = sqrtf(red[0]);
        if (v < 256) w1i[v] = n; else w1t[v - 256] = n;
    }
}

// ---------------------------------------------------------------------------
// MFMA Gram kernel (reads packed bf16): blk<256 -> G[b]=E_img E_img^T (R=36),
// else H[b]=E_cap E_cap^T (R=40). Frag-order staging via global_load_lds;
// A-frag == B-frag layout for 16x16x32, so one staged copy serves both sides.
// ---------------------------------------------------------------------------
__launch_bounds__(256, 2)
__global__ void gram_kernel(const u16* __restrict__ imgw, const u16* __restrict__ capw,
                            float* __restrict__ G, float* __restrict__ H){
    __shared__ __align__(16) char gsm[6144];    // 3 tiles x 2 kk x 64 lanes x 16B
    int blk = blockIdx.x;
    int tid = threadIdx.x, lane = tid & 63;
    int wave = __builtin_amdgcn_readfirstlane(tid >> 6);
    int frow = lane & 15, q = lane >> 4;

    const u16* E; float* Gout; int R;
    if (blk < NBAT){ E = imgw + (size_t)blk * 37 * D_EMB; Gout = G + (size_t)blk * 1296; R = 36; }
    else { int b = blk - NBAT; E = capw + (size_t)b * 41 * D_EMB; Gout = H + (size_t)b * 1600; R = 40; }

    {   // zero staging once (pad rows stay zero)
        uint4 z = {0u,0u,0u,0u};
        for (int off = tid * 16; off < 6144; off += 4096) *(uint4*)(gsm + off) = z;
    }

    // staging groups g = kk*3 + t, g in [0,6)
    const u16* gsrc[2]; int goff[2]; bool gval[2];
    #pragma unroll
    for (int j = 0; j < 2; ++j){
        int g = wave + j * 4;
        gval[j] = false; gsrc[j] = E; goff[j] = 0;
        if (g < 6){
            int kk = g / 3, t = g - kk * 3;
            int row = t * 16 + frow;
            gsrc[j] = E + (size_t)row * D_EMB + kk * 32 + q * 8;
            goff[j] = g * 1024;
            gval[j] = (row < R);
        }
    }

    int wm = wave >> 1, wn = wave & 1;   // tm in {wm, wm+2} (trimmed to <3), tn likewise
    int nTm = wm ? 1 : 2, nTn = wn ? 1 : 2;
    f32x4 acc[2][2];
    #pragma unroll
    for (int a = 0; a < 2; ++a)
        #pragma unroll
        for (int b = 0; b < 2; ++b) acc[a][b] = (f32x4){0.f,0.f,0.f,0.f};

    for (int c = 0; c < 16; ++c){
        __syncthreads();
        #pragma unroll
        for (int j = 0; j < 2; ++j){
            if (gval[j]){
                __builtin_amdgcn_global_load_lds(
                    (const AS1 void*)(const void*)(gsrc[j] + c * 64),
                    (AS3 void*)(void*)(gsm + goff[j] + lane * 16),
                    16, 0, 0);
            }
        }
        __syncthreads();
        #pragma unroll
        for (int kk = 0; kk < 2; ++kk){
            bf16x8 fA[2], fB[2];
            #pragma unroll
            for (int mi = 0; mi < 2; ++mi)
                if (mi < nTm) fA[mi] = *(const bf16x8*)(gsm + ((kk * 3 + (wm + mi * 2)) * 64 + lane) * 16);
            #pragma unroll
            for (int ni = 0; ni < 2; ++ni)
                if (ni < nTn) fB[ni] = *(const bf16x8*)(gsm + ((kk * 3 + (wn + ni * 2)) * 64 + lane) * 16);
            #pragma unroll
            for (int mi = 0; mi < 2; ++mi)
                if (mi < nTm)
                    #pragma unroll
                    for (int ni = 0; ni < 2; ++ni)
                        if (ni < nTn)
                            acc[mi][ni] = __builtin_amdgcn_mfma_f32_16x16x32_bf16(
                                fA[mi], fB[ni], acc[mi][ni], 0, 0, 0);
        }
    }

    // epilogue: C row = tm*16 + q*4+g (A-side), col = tn*16 + frow (B-side)
    #pragma unroll
    for (int mi = 0; mi < 2; ++mi){
        if (mi < nTm){
            int tm = wm + mi * 2;
            #pragma unroll
            for (int ni = 0; ni < 2; ++ni){
                if (ni < nTn){
                    int tn = wn + ni * 2;
                    int col = tn * 16 + frow;
                    if (col < R){
                        #pragma unroll
                        for (int g = 0; g < 4; ++g){
                            int row = tm * 16 + q * 4 + g;
                            if (row < R) Gout[row * R + col] = acc[mi][ni][g];
                        }
                    }
                }
            }
        }
    }
}

// ---------------------------------------------------------------------------
// Fused main kernel. One block = 2 images x 2 captions.
// LDS 26624 B; __launch_bounds__(256,5): 5 blocks/CU (133 KB LDS), 102-reg
// budget -> post-phase u[36]/v[40] fit without scratch spill (R3's (256,6)
// gave an 85-reg budget -> 225 MB of scratch traffic).
// ---------------------------------------------------------------------------
__launch_bounds__(256, 5)
__global__ void fused_kernel(const u16* __restrict__ imgw, const u16* __restrict__ capw,
                             const float* __restrict__ G, const float* __restrict__ H,
                             const float* __restrict__ w1i, const float* __restrict__ w1t,
                             float* __restrict__ out){
    __shared__ __align__(16) char smem[26624];
    float* Call = (float*)smem;                 // overlay after GEMM: [74][85]
    float* rnb  = (float*)(smem + 25160);       // [4][36]
    float* cnb  = (float*)(smem + 25736);       // [4][40]

    int tid  = threadIdx.x;
    int lane = tid & 63;
    int wave = __builtin_amdgcn_readfirstlane(tid >> 6);
    int frow = lane & 15, q = lane >> 4;

    int lin = blockIdx.x;
    int pan = lin >> 10;                 // panel swizzle for L2 reuse
    int rem = lin & 1023;
    int b_t = rem >> 3;
    int i_t = (pan << 3) | (rem & 7);
    int b0 = b_t * 2, i0 = i_t * 2;
    const u16* Ag = imgw + (size_t)b0 * 37 * D_EMB;   // 74 rows
    const u16* Bg = capw + (size_t)i0 * 41 * D_EMB;   // 82 rows

    {   // zero staging region once (pad slots stay zero forever)
        uint4 z = {0u,0u,0u,0u};
        for (int off = tid * 16; off < 22528; off += 4096) *(uint4*)(smem + off) = z;
    }

    // staging groups: A g in [0,10): tm=g%5, kk=g/5, off g*1024
    //                 B g in [10,22): gb=g-10, tn=gb%6, kk=gb/6, off 10240+gb*1024
    const u16* gsrc[6]; int goff[6]; bool gval[6];
    #pragma unroll
    for (int j = 0; j < 6; ++j){
        int g = wave + j * 4;
        gval[j] = false; gsrc[j] = Ag; goff[j] = 0;
        if (g < 22){
            if (g < 10){
                int tm = g % 5, kk = g / 5;
                int row = tm * 16 + frow;
                gsrc[j] = Ag + (size_t)row * D_EMB + kk * 32 + q * 8;
                goff[j] = g * 1024;
                gval[j] = (row < 74);
            } else {
                int gb = g - 10;
                int tn = gb % 6, kk = gb / 6;
                int row = tn * 16 + frow;
                gsrc[j] = Bg + (size_t)row * D_EMB + kk * 32 + q * 8;
                goff[j] = 10240 + gb * 1024;
                gval[j] = (row < 82);
            }
        }
    }

    int wm = wave >> 1, wn = wave & 1;     // 2x2 wave grid over 5x6 MFMA tiles
    int nTm = wm ? 2 : 3;                  // m-tiles {wm, wm+2, wm+4} < 5
    f32x4 acc[3][3];
    #pragma unroll
    for (int aa = 0; aa < 3; ++aa)
        #pragma unroll
        for (int bb = 0; bb < 3; ++bb) acc[aa][bb] = (f32x4){0.f, 0.f, 0.f, 0.f};

    for (int c = 0; c < 16; ++c){          // K chunks of 64
        __syncthreads();                   // prev chunk's frag reads done
        #pragma unroll
        for (int j = 0; j < 6; ++j){
            if (gval[j]){
                __builtin_amdgcn_global_load_lds(
                    (const AS1 void*)(const void*)(gsrc[j] + c * 64),
                    (AS3 void*)(void*)(smem + goff[j] + lane * 16),
                    16, 0, 0);
            }
        }
        __syncthreads();                   // drains vmcnt -> data in LDS
        #pragma unroll
        for (int kk = 0; kk < 2; ++kk){
            bf16x8 bfr[3];
            #pragma unroll
            for (int ni = 0; ni < 3; ++ni){
                int tn = wn + ni * 2;
                bfr[ni] = *(const bf16x8*)(smem + 10240 + ((kk * 6 + tn) * 64 + lane) * 16);
            }
            #pragma unroll
            for (int mi = 0; mi < 3; ++mi){
                if (mi < nTm){
                    int tm = wm + mi * 2;
                    bf16x8 af = *(const bf16x8*)(smem + ((kk * 5 + tm) * 64 + lane) * 16);
                    #pragma unroll
                    for (int ni = 0; ni < 3; ++ni){
                        acc[mi][ni] = __builtin_amdgcn_mfma_f32_16x16x32_bf16(
                            af, bfr[ni], acc[mi][ni], 0, 0, 0);
                    }
                }
            }
        }
    }
    __syncthreads();                       // all frag reads done before overlay

    // C/D layout: col = lane&15 (B-row), row = (lane>>4)*4 + reg (A-row)
    #pragma unroll
    for (int mi = 0; mi < 3; ++mi){
        if (mi < nTm){
            int tm = wm + mi * 2;
            #pragma unroll
            for (int ni = 0; ni < 3; ++ni){
                int tn = wn + ni * 2;
                int col = tn * 16 + frow;
                int rbase = tm * 16 + q * 4;
                if (col < 82){
                    #pragma unroll
                    for (int g = 0; g < 4; ++g){
                        int rowc = rbase + g;
                        if (rowc < 74) Call[rowc * 85 + col] = acc[mi][ni][g];
                    }
                }
            }
        }
    }
    __syncthreads();

    // ----- post-processing: one wave per (b,i) pair, weights in registers -----
    int pb = wave >> 1, pi = wave & 1;
    int bg = b0 + pb, ig = i0 + pi;
    const float* Sv = Call + (pb * 37) * 85 + pi * 41;  // S[r*85+l]; p[r]=S[r*85+40]; qv[l]=S[36*85+l]
    const float* Gb = G + (size_t)bg * 1296;
    const float* Hi = H + (size_t)ig * 1600;
    float w1_txt = w1t[ig];
    float w1_img = w1i[bg];

    // ---- t2i ----
    {   // row norms over words (lanes = regions)
        int r0 = (lane < 36) ? lane : 35;
        float s = 0.f;
        #pragma unroll
        for (int l = 0; l < 40; ++l){ float x = leaky(Sv[r0 * 85 + l]); s = fmaf(x, x, s); }
        if (lane < 36) rnb[wave * 36 + lane] = 1.f / (sqrtf(s) + 1e-8f);
    }
    float t2i_sum;
    {   // lanes = words
        int lc = (lane < 40) ? lane : 39;
        float u[36], dd = 0.f, num = 0.f;
        #pragma unroll
        for (int r = 0; r < 36; ++r){
            float x = leaky(Sv[r * 85 + lc]);
            float e = __expf(9.0f * x * rnb[wave * 36 + r]);
            u[r] = e; dd += e;
            num = fmaf(e, Sv[r * 85 + 40], num);
        }
        float zz = 0.f;
        #pragma unroll
        for (int rr = 0; rr < 36; ++rr){
            float t = 0.f;
            #pragma unroll
            for (int r2 = rr + 1; r2 < 36; ++r2) t = fmaf(Gb[rr * 36 + r2], u[r2], t);
            zz += (2.f * t + Gb[rr * 36 + rr] * u[rr]) * u[rr];
        }
        float w2s = sqrtf(fmaxf(zz, 0.f));
        float sim = (num / dd) / fmaxf(w1_txt * w2s / dd, 1e-8f);
        sim = (lane < 40) ? sim : 0.f;
        #pragma unroll
        for (int off = 32; off > 0; off >>= 1) sim += __shfl_down(sim, off);
        t2i_sum = sim;
    }

    // ---- i2t ----
    {   // column norms over regions (lanes = words)
        int l0 = (lane < 40) ? lane : 39;
        float s = 0.f;
        #pragma unroll
        for (int r = 0; r < 36; ++r){ float x = leaky(Sv[r * 85 + l0]); s = fmaf(x, x, s); }
        if (lane < 40) cnb[wave * 40 + lane] = 1.f / (sqrtf(s) + 1e-8f);
    }
    float i2t_sum;
    {   // lanes = regions
        int rc = (lane < 36) ? lane : 35;
        float v[40], dd = 0.f, num = 0.f;
        #pragma unroll
        for (int l = 0; l < 40; ++l){
            float x = leaky(Sv[rc * 85 + l]);
            float e = __expf(9.0f * x * cnb[wave * 40 + l]);
            v[l] = e; dd += e;
            num = fmaf(e, Sv[36 * 85 + l], num);
        }
        float zz = 0.f;
        #pragma unroll
        for (int ll = 0; ll < 40; ++ll){
            float t = 0.f;
            #pragma unroll
            for (int l2 = ll + 1; l2 < 40; ++l2) t = fmaf(Hi[ll * 40 + l2], v[l2], t);
            zz += (2.f * t + Hi[ll * 40 + ll] * v[ll]) * v[ll];
        }
        float w2s = sqrtf(fmaxf(zz, 0.f));
        float sim = (num / dd) / fmaxf(w1_img * w2s / dd, 1e-8f);
        sim = (lane < 36) ? sim : 0.f;
        #pragma unroll
        for (int off = 32; off > 0; off >>= 1) sim += __shfl_down(sim, off);
        i2t_sum = sim;
    }

    if (lane == 0)
        out[bg * 256 + ig] = t2i_sum * (1.f / 40.f) + i2t_sum * (1.f / 36.f) + Sv[36 * 85 + 40];
}

// ---------------------------------------------------------------------------
extern "C" void kernel_launch(void* const* d_in, const int* in_sizes, int n_in,
                              void* d_out, int out_size, void* d_ws, size_t ws_size,
                              hipStream_t stream){
    const float* pool_img = (const float*)d_in[0];
    const float* img_emb  = (const float*)d_in[1];
    const float* pool_txt = (const float*)d_in[2];
    const float* cap_emb  = (const float*)d_in[3];
    float* out = (float*)d_out;

    char* ws = (char*)d_ws;                         // needs ~43.9 MB
    size_t o = 0;
    u16* imgw = (u16*)(ws + o);  o += (size_t)256 * 37 * 1024 * 2;
    u16* capw = (u16*)(ws + o);  o += (size_t)256 * 41 * 1024 * 2;
    float* G  = (float*)(ws + o); o += (size_t)256 * 36 * 36 * 4;
    float* H  = (float*)(ws + o); o += (size_t)256 * 40 * 40 * 4;
    float* w1i = (float*)(ws + o); o += 1024;
    float* w1t = (float*)(ws + o); o += 1024;

    pack_kernel<<<19968, 256, 0, stream>>>(pool_img, img_emb, pool_txt, cap_emb, imgw, capw);
    norm_kernel<<<512, 256, 0, stream>>>(pool_img, pool_txt, w1i, w1t);
    gram_kernel<<<512, 256, 0, stream>>>(imgw, capw, G, H);
    fused_kernel<<<16384, 256, 0, stream>>>(imgw, capw, G, H, w1i, w1t, out);
}

// Round 5
// 753.412 us; speedup vs baseline: 1.1511x; 1.1511x over previous
//
#include <hip/hip_runtime.h>

typedef unsigned short u16;
typedef __attribute__((ext_vector_type(8))) short bf16x8;   // 8 bf16 (4 VGPRs)
typedef __attribute__((ext_vector_type(4))) float f32x4;

#define D_EMB 1024
#define NBAT  256
#define AS1 __attribute__((address_space(1)))
#define AS3 __attribute__((address_space(3)))

__device__ __forceinline__ u16 f2bf(float f){
    unsigned int u = __float_as_uint(f);
    unsigned int r = (u + 0x7fffu + ((u >> 16) & 1u)) >> 16;  // RNE
    return (u16)r;
}
__device__ __forceinline__ float leaky(float x){ return x > 0.f ? x : 0.1f * x; }

// bf16-pair helpers for register-packed weight arrays (truncation pack: the
// high half of an fp32 IS a valid bf16-precision fp32; unpack = 1 VALU inst).
__device__ __forceinline__ unsigned pack2(float a, float b){
    return (__float_as_uint(a) >> 16) | (__float_as_uint(b) & 0xffff0000u);
}
__device__ __forceinline__ float unpk_lo(unsigned p){ return __uint_as_float(p << 16); }
__device__ __forceinline__ float unpk_hi(unsigned p){ return __uint_as_float(p & 0xffff0000u); }

// ---------------------------------------------------------------------------
// Pack img_emb(+pool_img as row 36) and cap_emb(+pool_txt as row 40) to bf16.
// imgw: [256][37][1024] bf16, capw: [256][41][1024] bf16
// ---------------------------------------------------------------------------
__global__ void pack_kernel(const float* __restrict__ pool_img, const float* __restrict__ img_emb,
                            const float* __restrict__ pool_txt, const float* __restrict__ cap_emb,
                            u16* __restrict__ imgw, u16* __restrict__ capw){
    int row = blockIdx.x;            // 0..19967
    const float* src; u16* dst;
    if (row < NBAT * 37){
        int e = row / 37, rr = row - e * 37;
        src = (rr < 36) ? (img_emb + ((size_t)e * 36 + rr) * D_EMB) : (pool_img + (size_t)e * D_EMB);
        dst = imgw + (size_t)row * D_EMB;
    } else {
        int r2 = row - NBAT * 37;
        int e = r2 / 41, rr = r2 - e * 41;
        src = (rr < 40) ? (cap_emb + ((size_t)e * 40 + rr) * D_EMB) : (pool_txt + (size_t)e * D_EMB);
        dst = capw + (size_t)r2 * D_EMB;
    }
    int t = threadIdx.x;             // 256 threads, 4 floats each
    float4 v = ((const float4*)src)[t];
    unsigned long long pk = (unsigned long long)f2bf(v.x)
        | ((unsigned long long)f2bf(v.y) << 16)
        | ((unsigned long long)f2bf(v.z) << 32)
        | ((unsigned long long)f2bf(v.w) << 48);
    *(unsigned long long*)(dst + (size_t)t * 4) = pk;
}

// ---------------------------------------------------------------------------
// Pool-vector norms
// ---------------------------------------------------------------------------
__global__ void norm_kernel(const float* __restrict__ pool_img, const float* __restrict__ pool_txt,
                            float* __restrict__ w1i, float* __restrict__ w1t){
    __shared__ float red[256];
    int v = blockIdx.x;              // 0..511
    const float* src = (v < 256) ? (pool_img + (size_t)v * D_EMB)
                                 : (pool_txt + (size_t)(v - 256) * D_EMB);
    int t = threadIdx.x;
    float4 x = ((const float4*)src)[t];
    red[t] = x.x*x.x + x.y*x.y + x.z*x.z + x.w*x.w;
    __syncthreads();
    for (int off = 128; off > 0; off >>= 1){
        if (t < off) red[t] += red[t + off];
        __syncthreads();
    }
    if (t == 0){
        float n = sqrtf(red[0]);
        if (v < 256) w1i[v] = n; else w1t[v - 256] = n;
    }
}

// ---------------------------------------------------------------------------
// MFMA Gram kernel (reads packed bf16): blk<256 -> G[b]=E_img E_img^T (R=36),
// else H[b]=E_cap E_cap^T (R=40). Frag-order staging via global_load_lds;
// A-frag == B-frag layout for 16x16x32, so one staged copy serves both sides.
// ---------------------------------------------------------------------------
__launch_bounds__(256, 2)
__global__ void gram_kernel(const u16* __restrict__ imgw, const u16* __restrict__ capw,
                            float* __restrict__ G, float* __restrict__ H){
    __shared__ __align__(16) char gsm[6144];    // 3 tiles x 2 kk x 64 lanes x 16B
    int blk = blockIdx.x;
    int tid = threadIdx.x, lane = tid & 63;
    int wave = __builtin_amdgcn_readfirstlane(tid >> 6);
    int frow = lane & 15, q = lane >> 4;

    const u16* E; float* Gout; int R;
    if (blk < NBAT){ E = imgw + (size_t)blk * 37 * D_EMB; Gout = G + (size_t)blk * 1296; R = 36; }
    else { int b = blk - NBAT; E = capw + (size_t)b * 41 * D_EMB; Gout = H + (size_t)b * 1600; R = 40; }

    {   // zero staging once (pad rows stay zero)
        uint4 z = {0u,0u,0u,0u};
        for (int off = tid * 16; off < 6144; off += 4096) *(uint4*)(gsm + off) = z;
    }

    // staging groups g = kk*3 + t, g in [0,6)
    const u16* gsrc[2]; int goff[2]; bool gval[2];
    #pragma unroll
    for (int j = 0; j < 2; ++j){
        int g = wave + j * 4;
        gval[j] = false; gsrc[j] = E; goff[j] = 0;
        if (g < 6){
            int kk = g / 3, t = g - kk * 3;
            int row = t * 16 + frow;
            gsrc[j] = E + (size_t)row * D_EMB + kk * 32 + q * 8;
            goff[j] = g * 1024;
            gval[j] = (row < R);
        }
    }

    int wm = wave >> 1, wn = wave & 1;   // tm in {wm, wm+2} (trimmed to <3), tn likewise
    int nTm = wm ? 1 : 2, nTn = wn ? 1 : 2;
    f32x4 acc[2][2];
    #pragma unroll
    for (int a = 0; a < 2; ++a)
        #pragma unroll
        for (int b = 0; b < 2; ++b) acc[a][b] = (f32x4){0.f,0.f,0.f,0.f};

    for (int c = 0; c < 16; ++c){
        __syncthreads();
        #pragma unroll
        for (int j = 0; j < 2; ++j){
            if (gval[j]){
                __builtin_amdgcn_global_load_lds(
                    (const AS1 void*)(const void*)(gsrc[j] + c * 64),
                    (AS3 void*)(void*)(gsm + goff[j] + lane * 16),
                    16, 0, 0);
            }
        }
        __syncthreads();
        #pragma unroll
        for (int kk = 0; kk < 2; ++kk){
            bf16x8 fA[2], fB[2];
            #pragma unroll
            for (int mi = 0; mi < 2; ++mi)
                if (mi < nTm) fA[mi] = *(const bf16x8*)(gsm + ((kk * 3 + (wm + mi * 2)) * 64 + lane) * 16);
            #pragma unroll
            for (int ni = 0; ni < 2; ++ni)
                if (ni < nTn) fB[ni] = *(const bf16x8*)(gsm + ((kk * 3 + (wn + ni * 2)) * 64 + lane) * 16);
            #pragma unroll
            for (int mi = 0; mi < 2; ++mi)
                if (mi < nTm)
                    #pragma unroll
                    for (int ni = 0; ni < 2; ++ni)
                        if (ni < nTn)
                            acc[mi][ni] = __builtin_amdgcn_mfma_f32_16x16x32_bf16(
                                fA[mi], fB[ni], acc[mi][ni], 0, 0, 0);
        }
    }

    // epilogue: C row = tm*16 + q*4+g (A-side), col = tn*16 + frow (B-side)
    #pragma unroll
    for (int mi = 0; mi < 2; ++mi){
        if (mi < nTm){
            int tm = wm + mi * 2;
            #pragma unroll
            for (int ni = 0; ni < 2; ++ni){
                if (ni < nTn){
                    int tn = wn + ni * 2;
                    int col = tn * 16 + frow;
                    if (col < R){
                        #pragma unroll
                        for (int g = 0; g < 4; ++g){
                            int row = tm * 16 + q * 4 + g;
                            if (row < R) Gout[row * R + col] = acc[mi][ni][g];
                        }
                    }
                }
            }
        }
    }
}

// ---------------------------------------------------------------------------
// Fused main kernel. One block = 2 images x 2 captions.
// LDS 26624 B; bounds (256,5): ~96-reg budget, even 48/48 arch/AGPR split
// (measured R2-R4 allocator behavior) -> post phase must fit 48 arch VGPRs:
// softmax weights packed as bf16 pairs (u:18, v:20 regs).
// XCD swizzle: blk&7 = XCD; each XCD owns 16 b-tiles (2.4 MB A resident in
// its 4 MB L2); 16 consecutive blocks on one XCD share each B-tile.
// ---------------------------------------------------------------------------
__launch_bounds__(256, 5)
__global__ void fused_kernel(const u16* __restrict__ imgw, const u16* __restrict__ capw,
                             const float* __restrict__ G, const float* __restrict__ H,
                             const float* __restrict__ w1i, const float* __restrict__ w1t,
                             float* __restrict__ out){
    __shared__ __align__(16) char smem[26624];
    float* Call = (float*)smem;                 // overlay after GEMM: [74][85]
    float* rnb  = (float*)(smem + 25160);       // [4][36]
    float* cnb  = (float*)(smem + 25736);       // [4][40]

    int tid  = threadIdx.x;
    int lane = tid & 63;
    int wave = __builtin_amdgcn_readfirstlane(tid >> 6);
    int frow = lane & 15, q = lane >> 4;

    int lin = blockIdx.x;
    int xcd = lin & 7;                   // XCD-aware swizzle (round-robin heuristic)
    int s   = lin >> 3;                  // 0..2047
    int b_t = (xcd << 4) | (s & 15);     // each XCD owns 16 b-tiles
    int i_t = s >> 4;                    // 0..127
    int b0 = b_t * 2, i0 = i_t * 2;
    const u16* Ag = imgw + (size_t)b0 * 37 * D_EMB;   // 74 rows
    const u16* Bg = capw + (size_t)i0 * 41 * D_EMB;   // 82 rows

    {   // zero staging region once (pad slots stay zero forever)
        uint4 z = {0u,0u,0u,0u};
        for (int off = tid * 16; off < 22528; off += 4096) *(uint4*)(smem + off) = z;
    }

    // staging groups: A g in [0,10): tm=g%5, kk=g/5, off g*1024
    //                 B g in [10,22): gb=g-10, tn=gb%6, kk=gb/6, off 10240+gb*1024
    const u16* gsrc[6]; int goff[6]; bool gval[6];
    #pragma unroll
    for (int j = 0; j < 6; ++j){
        int g = wave + j * 4;
        gval[j] = false; gsrc[j] = Ag; goff[j] = 0;
        if (g < 22){
            if (g < 10){
                int tm = g % 5, kk = g / 5;
                int row = tm * 16 + frow;
                gsrc[j] = Ag + (size_t)row * D_EMB + kk * 32 + q * 8;
                goff[j] = g * 1024;
                gval[j] = (row < 74);
            } else {
                int gb = g - 10;
                int tn = gb % 6, kk = gb / 6;
                int row = tn * 16 + frow;
                gsrc[j] = Bg + (size_t)row * D_EMB + kk * 32 + q * 8;
                goff[j] = 10240 + gb * 1024;
                gval[j] = (row < 82);
            }
        }
    }

    int wm = wave >> 1, wn = wave & 1;     // 2x2 wave grid over 5x6 MFMA tiles
    int nTm = wm ? 2 : 3;                  // m-tiles {wm, wm+2, wm+4} < 5
    f32x4 acc[3][3];
    #pragma unroll
    for (int aa = 0; aa < 3; ++aa)
        #pragma unroll
        for (int bb = 0; bb < 3; ++bb) acc[aa][bb] = (f32x4){0.f, 0.f, 0.f, 0.f};

    for (int c = 0; c < 16; ++c){          // K chunks of 64
        __syncthreads();                   // prev chunk's frag reads done
        #pragma unroll
        for (int j = 0; j < 6; ++j){
            if (gval[j]){
                __builtin_amdgcn_global_load_lds(
                    (const AS1 void*)(const void*)(gsrc[j] + c * 64),
                    (AS3 void*)(void*)(smem + goff[j] + lane * 16),
                    16, 0, 0);
            }
        }
        __syncthreads();                   // drains vmcnt -> data in LDS
        #pragma unroll
        for (int kk = 0; kk < 2; ++kk){
            bf16x8 bfr[3];
            #pragma unroll
            for (int ni = 0; ni < 3; ++ni){
                int tn = wn + ni * 2;
                bfr[ni] = *(const bf16x8*)(smem + 10240 + ((kk * 6 + tn) * 64 + lane) * 16);
            }
            #pragma unroll
            for (int mi = 0; mi < 3; ++mi){
                if (mi < nTm){
                    int tm = wm + mi * 2;
                    bf16x8 af = *(const bf16x8*)(smem + ((kk * 5 + tm) * 64 + lane) * 16);
                    #pragma unroll
                    for (int ni = 0; ni < 3; ++ni){
                        acc[mi][ni] = __builtin_amdgcn_mfma_f32_16x16x32_bf16(
                            af, bfr[ni], acc[mi][ni], 0, 0, 0);
                    }
                }
            }
        }
    }
    __syncthreads();                       // all frag reads done before overlay

    // C/D layout: col = lane&15 (B-row), row = (lane>>4)*4 + reg (A-row)
    #pragma unroll
    for (int mi = 0; mi < 3; ++mi){
        if (mi < nTm){
            int tm = wm + mi * 2;
            #pragma unroll
            for (int ni = 0; ni < 3; ++ni){
                int tn = wn + ni * 2;
                int col = tn * 16 + frow;
                int rbase = tm * 16 + q * 4;
                if (col < 82){
                    #pragma unroll
                    for (int g = 0; g < 4; ++g){
                        int rowc = rbase + g;
                        if (rowc < 74) Call[rowc * 85 + col] = acc[mi][ni][g];
                    }
                }
            }
        }
    }
    __syncthreads();

    // ----- post-processing: one wave per (b,i) pair, weights packed bf16 -----
    int pb = wave >> 1, pi = wave & 1;
    int bg = b0 + pb, ig = i0 + pi;
    const float* Sv = Call + (pb * 37) * 85 + pi * 41;  // S[r*85+l]; p[r]=S[r*85+40]; qv[l]=S[36*85+l]
    const float* Gb = G + (size_t)bg * 1296;
    const float* Hi = H + (size_t)ig * 1600;

    // ---- t2i ----
    {   // row norms over words (lanes = regions)
        int r0 = (lane < 36) ? lane : 35;
        float s2 = 0.f;
        #pragma unroll
        for (int l = 0; l < 40; ++l){ float x = leaky(Sv[r0 * 85 + l]); s2 = fmaf(x, x, s2); }
        if (lane < 36) rnb[wave * 36 + lane] = 1.f / (sqrtf(s2) + 1e-8f);
    }
    float t2i_sum;
    {   // lanes = words; u packed as 18 bf16 pairs
        int lc = (lane < 40) ? lane : 39;
        unsigned up[18];
        float dd = 0.f, num = 0.f;
        #pragma unroll
        for (int r = 0; r < 36; r += 2){
            float x0 = leaky(Sv[r * 85 + lc]);
            float e0 = __expf(9.0f * x0 * rnb[wave * 36 + r]);
            float x1 = leaky(Sv[(r + 1) * 85 + lc]);
            float e1 = __expf(9.0f * x1 * rnb[wave * 36 + r + 1]);
            dd += e0 + e1;
            num = fmaf(e0, Sv[r * 85 + 40], fmaf(e1, Sv[(r + 1) * 85 + 40], num));
            up[r >> 1] = pack2(e0, e1);
        }
        float zz = 0.f;
        #pragma unroll
        for (int rr = 0; rr < 36; ++rr){
            float urr = (rr & 1) ? unpk_hi(up[rr >> 1]) : unpk_lo(up[rr >> 1]);
            float t = 0.f;
            #pragma unroll
            for (int r2 = rr + 1; r2 < 36; ++r2){
                float ur2 = (r2 & 1) ? unpk_hi(up[r2 >> 1]) : unpk_lo(up[r2 >> 1]);
                t = fmaf(Gb[rr * 36 + r2], ur2, t);
            }
            zz += (2.f * t + Gb[rr * 36 + rr] * urr) * urr;
        }
        float w2s = sqrtf(fmaxf(zz, 0.f));
        float sim = num / fmaxf(w1t[ig] * w2s, 1e-8f);   // dd cancels: (num/dd)/(w1*w2s/dd)
        sim = (lane < 40) ? sim : 0.f;
        #pragma unroll
        for (int off = 32; off > 0; off >>= 1) sim += __shfl_down(sim, off);
        t2i_sum = sim;
    }

    // ---- i2t ----
    {   // column norms over regions (lanes = words)
        int l0 = (lane < 40) ? lane : 39;
        float s2 = 0.f;
        #pragma unroll
        for (int r = 0; r < 36; ++r){ float x = leaky(Sv[r * 85 + l0]); s2 = fmaf(x, x, s2); }
        if (lane < 40) cnb[wave * 40 + lane] = 1.f / (sqrtf(s2) + 1e-8f);
    }
    float i2t_sum;
    {   // lanes = regions; v packed as 20 bf16 pairs
        int rc = (lane < 36) ? lane : 35;
        unsigned vp[20];
        float dd = 0.f, num = 0.f;
        #pragma unroll
        for (int l = 0; l < 40; l += 2){
            float x0 = leaky(Sv[rc * 85 + l]);
            float e0 = __expf(9.0f * x0 * cnb[wave * 40 + l]);
            float x1 = leaky(Sv[rc * 85 + l + 1]);
            float e1 = __expf(9.0f * x1 * cnb[wave * 40 + l + 1]);
            dd += e0 + e1;
            num = fmaf(e0, Sv[36 * 85 + l], fmaf(e1, Sv[36 * 85 + l + 1], num));
            vp[l >> 1] = pack2(e0, e1);
        }
        float zz = 0.f;
        #pragma unroll
        for (int ll = 0; ll < 40; ++ll){
            float vll = (ll & 1) ? unpk_hi(vp[ll >> 1]) : unpk_lo(vp[ll >> 1]);
            float t = 0.f;
            #pragma unroll
            for (int l2 = ll + 1; l2 < 40; ++l2){
                float vl2 = (l2 & 1) ? unpk_hi(vp[l2 >> 1]) : unpk_lo(vp[l2 >> 1]);
                t = fmaf(Hi[ll * 40 + l2], vl2, t);
            }
            zz += (2.f * t + Hi[ll * 40 + ll] * vll) * vll;
        }
        float w2s = sqrtf(fmaxf(zz, 0.f));
        float sim = num / fmaxf(w1i[bg] * w2s, 1e-8f);
        sim = (lane < 36) ? sim : 0.f;
        #pragma unroll
        for (int off = 32; off > 0; off >>= 1) sim += __shfl_down(sim, off);
        i2t_sum = sim;
    }

    if (lane == 0)
        out[bg * 256 + ig] = t2i_sum * (1.f / 40.f) + i2t_sum * (1.f / 36.f) + Sv[36 * 85 + 40];
}

// ---------------------------------------------------------------------------
extern "C" void kernel_launch(void* const* d_in, const int* in_sizes, int n_in,
                              void* d_out, int out_size, void* d_ws, size_t ws_size,
                              hipStream_t stream){
    const float* pool_img = (const float*)d_in[0];
    const float* img_emb  = (const float*)d_in[1];
    const float* pool_txt = (const float*)d_in[2];
    const float* cap_emb  = (const float*)d_in[3];
    float* out = (float*)d_out;

    char* ws = (char*)d_ws;                         // needs ~43.9 MB
    size_t o = 0;
    u16* imgw = (u16*)(ws + o);  o += (size_t)256 * 37 * 1024 * 2;
    u16* capw = (u16*)(ws + o);  o += (size_t)256 * 41 * 1024 * 2;
    float* G  = (float*)(ws + o); o += (size_t)256 * 36 * 36 * 4;
    float* H  = (float*)(ws + o); o += (size_t)256 * 40 * 40 * 4;
    float* w1i = (float*)(ws + o); o += 1024;
    float* w1t = (float*)(ws + o); o += 1024;

    pack_kernel<<<19968, 256, 0, stream>>>(pool_img, img_emb, pool_txt, cap_emb, imgw, capw);
    norm_kernel<<<512, 256, 0, stream>>>(pool_img, pool_txt, w1i, w1t);
    gram_kernel<<<512, 256, 0, stream>>>(imgw, capw, G, H);
    fused_kernel<<<16384, 256, 0, stream>>>(imgw, capw, G, H, w1i, w1t, out);
}